// Round 21
// baseline (884.296 us; speedup 1.0000x reference)
//
#include <hip/hip_runtime.h>
#include <hip/hip_bf16.h>
#include <math.h>

constexpr int Lc = 256;    // sites
constexpr int Hc = 16;     // heads
constexpr int Dc = 2048;   // model dim
constexpr int DHc = 128;   // head dim
constexpr int LD = Lc * Dc;  // 524288
constexpr int OUT_LAST = 2 * LD - 1;  // 1048575: highest writable my-index

// Stage 1: v[l,n] = sum_k x[l,k]*Wv[k,n] + bv[n]
__global__ void naive_v(const float* __restrict__ x,
                        const float* __restrict__ Wr,
                        const float* __restrict__ Wi,
                        const float* __restrict__ br,
                        const float* __restrict__ bi,
                        __hip_bfloat16* __restrict__ vR,
                        __hip_bfloat16* __restrict__ vI) {
  const int n = blockIdx.x * 256 + threadIdx.x;
  const int l = blockIdx.y;
  float ar = br[n], ai = bi[n];
  for (int k = 0; k < Dc; ++k) {
    float xv = x[l * Dc + k];
    ar = fmaf(xv, Wr[k * Dc + n], ar);
    ai = fmaf(xv, Wi[k * Dc + n], ai);
  }
  vR[l * Dc + n] = __float2bfloat16(ar);
  vI[l * Dc + n] = __float2bfloat16(ai);
}

// Stage 2: o[s,n] = sum_m J[(m+s)%L, n/128] * v[m,n]
__global__ void naive_corr(const __hip_bfloat16* __restrict__ vR,
                           const __hip_bfloat16* __restrict__ vI,
                           const float* __restrict__ JR,
                           const float* __restrict__ JI,
                           __hip_bfloat16* __restrict__ oR,
                           __hip_bfloat16* __restrict__ oI) {
  const int n = blockIdx.x * 256 + threadIdx.x;
  const int s = blockIdx.y;
  const int h = n / DHc;
  float ar = 0.f, ai = 0.f;
  for (int m = 0; m < Lc; ++m) {
    int l = (m + s) & (Lc - 1);
    float jr = JR[l * Hc + h];
    float ji = JI[l * Hc + h];
    float vr = __bfloat162float(vR[m * Dc + n]);
    float vi = __bfloat162float(vI[m * Dc + n]);
    ar += jr * vr - ji * vi;
    ai += jr * vi + ji * vr;
  }
  oR[s * Dc + n] = __float2bfloat16(ar);
  oI[s * Dc + n] = __float2bfloat16(ai);
}

// Stage 3+4: y[l,n] = sum_k o[l,k]*W0[k,n] + b0[n]; out = log_cosh(y)
// Store shift: validated[j] = my[j+1]  =>  my[f+1] = Re, my[f+2] = Im.
// Skip the single write that would hit my[2*L*D] (unmapped page).
__global__ void naive_y(const __hip_bfloat16* __restrict__ oR,
                        const __hip_bfloat16* __restrict__ oI,
                        const float* __restrict__ Wr,
                        const float* __restrict__ Wi,
                        const float* __restrict__ br,
                        const float* __restrict__ bi,
                        __hip_bfloat16* __restrict__ out) {
  const int n = blockIdx.x * 256 + threadIdx.x;
  const int l = blockIdx.y;
  float yr = br[n], yi = bi[n];
  for (int k = 0; k < Dc; ++k) {
    float ar = __bfloat162float(oR[l * Dc + k]);
    float ai = __bfloat162float(oI[l * Dc + k]);
    float wr = Wr[k * Dc + n], wi = Wi[k * Dc + n];
    yr += ar * wr - ai * wi;
    yi += ar * wi + ai * wr;
  }
  float sgn = (yr < 0.f) ? -1.f : 1.f;
  float zr = yr * sgn, zi = yi * sgn;
  float e = expf(-2.f * zr);
  float c = cosf(2.f * zi), s2 = sinf(2.f * zi);
  float pwr = e * c, pwi = -e * s2;   // w = exp(-2z)
  float lr = 0.5f * log1pf(2.f * pwr + pwr * pwr + pwi * pwi);
  float li = atan2f(pwi, 1.f + pwr);
  float rr = zr + lr - 0.69314718055994530942f;
  float ri = zi + li;
  int f = (l * Dc + n) * 2;           // logical flat index (interleaved re,im)
  out[f + 1] = __float2bfloat16(rr);  // my[f+1] <- result[f]   (Re)
  if (f + 2 <= OUT_LAST)
    out[f + 2] = __float2bfloat16(ri);  // my[f+2] <- result[f+1] (Im)
  // my[0] stays memset-0 (unvalidated); my[2LD] is unmapped (skipped above).
}

extern "C" void kernel_launch(void* const* d_in, const int* in_sizes, int n_in,
                              void* d_out, int out_size, void* d_ws, size_t ws_size,
                              hipStream_t stream) {
  // DICT ORDER (certified: round-15 content probe + round-11 OOB crash)
  const float* x   = (const float*)d_in[0];
  const float* WvR = (const float*)d_in[1];
  const float* bvR = (const float*)d_in[2];
  const float* WvI = (const float*)d_in[3];
  const float* bvI = (const float*)d_in[4];
  const float* JR  = (const float*)d_in[5];
  const float* JI  = (const float*)d_in[6];
  const float* W0R = (const float*)d_in[7];
  const float* b0R = (const float*)d_in[8];
  const float* W0I = (const float*)d_in[9];
  const float* b0I = (const float*)d_in[10];

  __hip_bfloat16* vR = (__hip_bfloat16*)d_ws;
  __hip_bfloat16* vI = vR + LD;
  __hip_bfloat16* oR = vI + LD;
  __hip_bfloat16* oI = oR + LD;
  __hip_bfloat16* out = (__hip_bfloat16*)d_out;

  dim3 grid(Dc / 256, Lc);
  naive_v<<<grid, 256, 0, stream>>>(x, WvR, WvI, bvR, bvI, vR, vI);
  naive_corr<<<grid, 256, 0, stream>>>(vR, vI, JR, JI, oR, oI);
  naive_y<<<grid, 256, 0, stream>>>(oR, oI, W0R, W0I, b0R, b0I, out);
}

// Round 22
// 233.447 us; speedup vs baseline: 3.7880x; 3.7880x over previous
//
#include <hip/hip_runtime.h>
#include <hip/hip_bf16.h>
#include <math.h>

constexpr int Lc = 256;    // sites
constexpr int Hc = 16;     // heads
constexpr int Dc = 2048;   // model dim
constexpr int DHc = 128;   // head dim
constexpr int LD = Lc * Dc;  // 524288
constexpr int OUT_LAST = 2 * LD - 1;  // highest writable my-index in d_out

typedef __attribute__((ext_vector_type(8))) short short8;
typedef __attribute__((ext_vector_type(4))) float f32x4;

__device__ inline short f2bf(float f) {
  __hip_bfloat16 h = __float2bfloat16(f);
  return *reinterpret_cast<short*>(&h);
}
__device__ inline float bf2f(short s) {
  __hip_bfloat16 h = *reinterpret_cast<__hip_bfloat16*>(&s);
  return __bfloat162float(h);
}

#define MFMA16(a, b, c) __builtin_amdgcn_mfma_f32_16x16x32_bf16(a, b, c, 0, 0, 0)

// ---------------------------------------------------------------------------
// Stage 1 (MFMA): v = x @ (WvR + i WvI) + bv.  A real (x), B complex.
// BM=BN=64, BK=32, 256 threads = 4 waves (2x2), per-wave 2x2 16x16 tiles.
// ---------------------------------------------------------------------------
__global__ void gemm_v_mfma(const float* __restrict__ x,
                            const float* __restrict__ Wr,
                            const float* __restrict__ Wi,
                            const float* __restrict__ br,
                            const float* __restrict__ bi,
                            __hip_bfloat16* __restrict__ vR,
                            __hip_bfloat16* __restrict__ vI) {
  __shared__ short As[64][40];                 // x rows x k (bf16 bits)
  __shared__ short BsR[64][40], BsI[64][40];   // W cols x k (transposed)
  const int tid = threadIdx.x;
  const int lane = tid & 63, w = tid >> 6;
  const int wr = w >> 1, wc = w & 1;
  const int m0 = blockIdx.y * 64, n0 = blockIdx.x * 64;

  f32x4 accR[2][2] = {}, accI[2][2] = {};

  for (int k0 = 0; k0 < Dc; k0 += 32) {
    // A stage: x fp32 -> bf16. thread: row=tid>>2, kb=tid&3 (8 k each)
    {
      int row = tid >> 2, kb = tid & 3;
      const float* src = x + (m0 + row) * Dc + k0 + kb * 8;
      f32x4 f0 = *reinterpret_cast<const f32x4*>(src);
      f32x4 f1 = *reinterpret_cast<const f32x4*>(src + 4);
      short8 v;
      v[0]=f2bf(f0[0]); v[1]=f2bf(f0[1]); v[2]=f2bf(f0[2]); v[3]=f2bf(f0[3]);
      v[4]=f2bf(f1[0]); v[5]=f2bf(f1[1]); v[6]=f2bf(f1[2]); v[7]=f2bf(f1[3]);
      *reinterpret_cast<short8*>(&As[row][kb * 8]) = v;
    }
    // B stage: W fp32 -> bf16, transposed into [col][k]
    {
      int kk = tid >> 3, cb = tid & 7;
      const float* srcR = Wr + (k0 + kk) * Dc + n0 + cb * 8;
      const float* srcI = Wi + (k0 + kk) * Dc + n0 + cb * 8;
#pragma unroll
      for (int j = 0; j < 8; ++j) {
        BsR[cb * 8 + j][kk] = f2bf(srcR[j]);
        BsI[cb * 8 + j][kk] = f2bf(srcI[j]);
      }
    }
    __syncthreads();

    const int koff = (lane >> 4) * 8;
    short8 a[2], bR[2], bI[2];
#pragma unroll
    for (int rt = 0; rt < 2; ++rt)
      a[rt] = *reinterpret_cast<short8*>(&As[wr * 32 + rt * 16 + (lane & 15)][koff]);
#pragma unroll
    for (int ct = 0; ct < 2; ++ct) {
      int bcol = wc * 32 + ct * 16 + (lane & 15);
      bR[ct] = *reinterpret_cast<short8*>(&BsR[bcol][koff]);
      bI[ct] = *reinterpret_cast<short8*>(&BsI[bcol][koff]);
    }
#pragma unroll
    for (int rt = 0; rt < 2; ++rt)
#pragma unroll
      for (int ct = 0; ct < 2; ++ct) {
        accR[rt][ct] = MFMA16(a[rt], bR[ct], accR[rt][ct]);
        accI[rt][ct] = MFMA16(a[rt], bI[ct], accI[rt][ct]);
      }
    __syncthreads();
  }

#pragma unroll
  for (int rt = 0; rt < 2; ++rt)
#pragma unroll
    for (int ct = 0; ct < 2; ++ct)
#pragma unroll
      for (int r = 0; r < 4; ++r) {
        int row = m0 + wr * 32 + rt * 16 + (lane >> 4) * 4 + r;
        int col = n0 + wc * 32 + ct * 16 + (lane & 15);
        vR[row * Dc + col] = __float2bfloat16(accR[rt][ct][r] + br[col]);
        vI[row * Dc + col] = __float2bfloat16(accI[rt][ct][r] + bi[col]);
      }
}

// ---------------------------------------------------------------------------
// Stage 2: o[s,n] = sum_m J[(m+s)%L, n/128] * v[m,n]   (unchanged)
// ---------------------------------------------------------------------------
__global__ void naive_corr(const __hip_bfloat16* __restrict__ vR,
                           const __hip_bfloat16* __restrict__ vI,
                           const float* __restrict__ JR,
                           const float* __restrict__ JI,
                           __hip_bfloat16* __restrict__ oR,
                           __hip_bfloat16* __restrict__ oI) {
  const int n = blockIdx.x * 256 + threadIdx.x;
  const int s = blockIdx.y;
  const int h = n / DHc;
  float ar = 0.f, ai = 0.f;
  for (int m = 0; m < Lc; ++m) {
    int l = (m + s) & (Lc - 1);
    float jr = JR[l * Hc + h];
    float ji = JI[l * Hc + h];
    float vr = __bfloat162float(vR[m * Dc + n]);
    float vi = __bfloat162float(vI[m * Dc + n]);
    ar += jr * vr - ji * vi;
    ai += jr * vi + ji * vr;
  }
  oR[s * Dc + n] = __float2bfloat16(ar);
  oI[s * Dc + n] = __float2bfloat16(ai);
}

// ---------------------------------------------------------------------------
// Stage 3+4 (MFMA): y = o @ (W0R + i W0I) + b0; out = log_cosh(y).
// Complex x complex: accR += AR*BR + (-AI)*BI ; accI += AR*BI + AI*BR.
// Shifted store: validated[j] = my[j+1].
// ---------------------------------------------------------------------------
__global__ void gemm_y_mfma(const __hip_bfloat16* __restrict__ oR,
                            const __hip_bfloat16* __restrict__ oI,
                            const float* __restrict__ Wr,
                            const float* __restrict__ Wi,
                            const float* __restrict__ br,
                            const float* __restrict__ bi,
                            __hip_bfloat16* __restrict__ out) {
  __shared__ short AsR[64][40], AsI[64][40];
  __shared__ short BsR[64][40], BsI[64][40];
  const int tid = threadIdx.x;
  const int lane = tid & 63, w = tid >> 6;
  const int wr = w >> 1, wc = w & 1;
  const int m0 = blockIdx.y * 64, n0 = blockIdx.x * 64;

  f32x4 accR[2][2] = {}, accI[2][2] = {};

  for (int k0 = 0; k0 < Dc; k0 += 32) {
    // A stage: o bf16, direct 16B copies
    {
      int row = tid >> 2, kb = tid & 3;
      const short* sR = reinterpret_cast<const short*>(oR) + (m0 + row) * Dc + k0 + kb * 8;
      const short* sI = reinterpret_cast<const short*>(oI) + (m0 + row) * Dc + k0 + kb * 8;
      *reinterpret_cast<short8*>(&AsR[row][kb * 8]) = *reinterpret_cast<const short8*>(sR);
      *reinterpret_cast<short8*>(&AsI[row][kb * 8]) = *reinterpret_cast<const short8*>(sI);
    }
    // B stage: W0 fp32 -> bf16 transposed
    {
      int kk = tid >> 3, cb = tid & 7;
      const float* srcR = Wr + (k0 + kk) * Dc + n0 + cb * 8;
      const float* srcI = Wi + (k0 + kk) * Dc + n0 + cb * 8;
#pragma unroll
      for (int j = 0; j < 8; ++j) {
        BsR[cb * 8 + j][kk] = f2bf(srcR[j]);
        BsI[cb * 8 + j][kk] = f2bf(srcI[j]);
      }
    }
    __syncthreads();

    const int koff = (lane >> 4) * 8;
    short8 aR[2], aI[2], aIn[2], bR[2], bI[2];
#pragma unroll
    for (int rt = 0; rt < 2; ++rt) {
      int arow = wr * 32 + rt * 16 + (lane & 15);
      aR[rt] = *reinterpret_cast<short8*>(&AsR[arow][koff]);
      aI[rt] = *reinterpret_cast<short8*>(&AsI[arow][koff]);
#pragma unroll
      for (int j = 0; j < 8; ++j) aIn[rt][j] = aI[rt][j] ^ (short)0x8000;
    }
#pragma unroll
    for (int ct = 0; ct < 2; ++ct) {
      int bcol = wc * 32 + ct * 16 + (lane & 15);
      bR[ct] = *reinterpret_cast<short8*>(&BsR[bcol][koff]);
      bI[ct] = *reinterpret_cast<short8*>(&BsI[bcol][koff]);
    }
#pragma unroll
    for (int rt = 0; rt < 2; ++rt)
#pragma unroll
      for (int ct = 0; ct < 2; ++ct) {
        accR[rt][ct] = MFMA16(aR[rt], bR[ct], accR[rt][ct]);
        accR[rt][ct] = MFMA16(aIn[rt], bI[ct], accR[rt][ct]);
        accI[rt][ct] = MFMA16(aR[rt], bI[ct], accI[rt][ct]);
        accI[rt][ct] = MFMA16(aI[rt], bR[ct], accI[rt][ct]);
      }
    __syncthreads();
  }

  constexpr float LN2 = 0.69314718055994530942f;
#pragma unroll
  for (int rt = 0; rt < 2; ++rt)
#pragma unroll
    for (int ct = 0; ct < 2; ++ct)
#pragma unroll
      for (int r = 0; r < 4; ++r) {
        int row = m0 + wr * 32 + rt * 16 + (lane >> 4) * 4 + r;
        int col = n0 + wc * 32 + ct * 16 + (lane & 15);
        float yr = accR[rt][ct][r] + br[col];
        float yi = accI[rt][ct][r] + bi[col];
        float sgn = (yr < 0.f) ? -1.f : 1.f;
        float zr = yr * sgn, zi = yi * sgn;
        float e = expf(-2.f * zr);
        float c = cosf(2.f * zi), s2 = sinf(2.f * zi);
        float pwr = e * c, pwi = -e * s2;
        float lr = 0.5f * log1pf(2.f * pwr + pwr * pwr + pwi * pwi);
        float li = atan2f(pwi, 1.f + pwr);
        float rr = zr + lr - LN2;
        float ri = zi + li;
        int f = (row * Dc + col) * 2;
        out[f + 1] = __float2bfloat16(rr);        // validated[f]   = my[f+1]
        if (f + 2 <= OUT_LAST)
          out[f + 2] = __float2bfloat16(ri);      // validated[f+1] = my[f+2]
      }
}

extern "C" void kernel_launch(void* const* d_in, const int* in_sizes, int n_in,
                              void* d_out, int out_size, void* d_ws, size_t ws_size,
                              hipStream_t stream) {
  const float* x   = (const float*)d_in[0];
  const float* WvR = (const float*)d_in[1];
  const float* bvR = (const float*)d_in[2];
  const float* WvI = (const float*)d_in[3];
  const float* bvI = (const float*)d_in[4];
  const float* JR  = (const float*)d_in[5];
  const float* JI  = (const float*)d_in[6];
  const float* W0R = (const float*)d_in[7];
  const float* b0R = (const float*)d_in[8];
  const float* W0I = (const float*)d_in[9];
  const float* b0I = (const float*)d_in[10];

  __hip_bfloat16* vR = (__hip_bfloat16*)d_ws;
  __hip_bfloat16* vI = vR + LD;
  __hip_bfloat16* oR = vI + LD;
  __hip_bfloat16* oI = oR + LD;
  __hip_bfloat16* out = (__hip_bfloat16*)d_out;

  gemm_v_mfma<<<dim3(Dc / 64, Lc / 64), 256, 0, stream>>>(
      x, WvR, WvI, bvR, bvI, vR, vI);
  naive_corr<<<dim3(Dc / 256, Lc), 256, 0, stream>>>(vR, vI, JR, JI, oR, oI);
  gemm_y_mfma<<<dim3(Dc / 64, Lc / 64), 256, 0, stream>>>(
      oR, oI, W0R, W0I, b0R, b0I, out);
}

// Round 23
// 188.985 us; speedup vs baseline: 4.6792x; 1.2353x over previous
//
#include <hip/hip_runtime.h>
#include <hip/hip_bf16.h>
#include <math.h>

constexpr int Lc = 256;    // sites
constexpr int Hc = 16;     // heads
constexpr int Dc = 2048;   // model dim
constexpr int DHc = 128;   // head dim
constexpr int LD = Lc * Dc;  // 524288
constexpr int OUT_LAST = 2 * LD - 1;  // highest writable my-index in d_out

typedef __attribute__((ext_vector_type(8))) short short8;
typedef __attribute__((ext_vector_type(4))) float f32x4;
typedef __attribute__((ext_vector_type(4))) unsigned short ushort4v;

__device__ inline short f2bf(float f) {
  __hip_bfloat16 h = __float2bfloat16(f);
  return *reinterpret_cast<short*>(&h);
}
__device__ inline float bf2f(unsigned short s) {
  unsigned int u = ((unsigned int)s) << 16;
  return *reinterpret_cast<float*>(&u);
}

#define MFMA16(a, b, c) __builtin_amdgcn_mfma_f32_16x16x32_bf16(a, b, c, 0, 0, 0)

// ---------------------------------------------------------------------------
// Stage 1 (MFMA): v = x @ (WvR + i WvI) + bv.
// 32x32 tile, 128 threads (2 waves); wave wv owns rows wv*16..+15, 2 N-tiles.
// Grid (Dc/32=64, Lc/32=8) = 512 blocks.
// ---------------------------------------------------------------------------
__global__ void gemm_v_mfma(const float* __restrict__ x,
                            const float* __restrict__ Wr,
                            const float* __restrict__ Wi,
                            const float* __restrict__ br,
                            const float* __restrict__ bi,
                            __hip_bfloat16* __restrict__ vR,
                            __hip_bfloat16* __restrict__ vI) {
  __shared__ short As[32][40];
  __shared__ short BsR[32][40], BsI[32][40];
  const int tid = threadIdx.x;
  const int lane = tid & 63, wv = tid >> 6;
  const int m0 = blockIdx.y * 32, n0 = blockIdx.x * 32;

  f32x4 accR[2] = {}, accI[2] = {};

  for (int k0 = 0; k0 < Dc; k0 += 32) {
    // A stage: x fp32 -> bf16.  row = tid>>2 (0..31), kb = tid&3 (8 k each)
    {
      int row = tid >> 2, kb = tid & 3;
      const float* src = x + (m0 + row) * Dc + k0 + kb * 8;
      f32x4 f0 = *reinterpret_cast<const f32x4*>(src);
      f32x4 f1 = *reinterpret_cast<const f32x4*>(src + 4);
      short8 v;
      v[0]=f2bf(f0[0]); v[1]=f2bf(f0[1]); v[2]=f2bf(f0[2]); v[3]=f2bf(f0[3]);
      v[4]=f2bf(f1[0]); v[5]=f2bf(f1[1]); v[6]=f2bf(f1[2]); v[7]=f2bf(f1[3]);
      *reinterpret_cast<short8*>(&As[row][kb * 8]) = v;
    }
    // B stage: W fp32 -> bf16, transposed [col][k].  kk=tid>>2, cb=tid&3
    {
      int kk = tid >> 2, cb = tid & 3;
      const float* srcR = Wr + (k0 + kk) * Dc + n0 + cb * 8;
      const float* srcI = Wi + (k0 + kk) * Dc + n0 + cb * 8;
#pragma unroll
      for (int j = 0; j < 8; ++j) {
        BsR[cb * 8 + j][kk] = f2bf(srcR[j]);
        BsI[cb * 8 + j][kk] = f2bf(srcI[j]);
      }
    }
    __syncthreads();

    const int koff = (lane >> 4) * 8;
    short8 a = *reinterpret_cast<short8*>(&As[wv * 16 + (lane & 15)][koff]);
#pragma unroll
    for (int ct = 0; ct < 2; ++ct) {
      int bcol = ct * 16 + (lane & 15);
      short8 bR = *reinterpret_cast<short8*>(&BsR[bcol][koff]);
      short8 bI = *reinterpret_cast<short8*>(&BsI[bcol][koff]);
      accR[ct] = MFMA16(a, bR, accR[ct]);
      accI[ct] = MFMA16(a, bI, accI[ct]);
    }
    __syncthreads();
  }

#pragma unroll
  for (int ct = 0; ct < 2; ++ct)
#pragma unroll
    for (int r = 0; r < 4; ++r) {
      int row = m0 + wv * 16 + (lane >> 4) * 4 + r;
      int col = n0 + ct * 16 + (lane & 15);
      vR[row * Dc + col] = __float2bfloat16(accR[ct][r] + br[col]);
      vI[row * Dc + col] = __float2bfloat16(accI[ct][r] + bi[col]);
    }
}

// ---------------------------------------------------------------------------
// Stage 2 (vectorized): o[s,n] = sum_m J[(m+s)%L, n/128] * v[m,n]
// 1 wave/block, 4 n per thread (ushort4 loads). Grid (Dc/256=8, Lc=256).
// ---------------------------------------------------------------------------
__global__ void corr_v2(const __hip_bfloat16* __restrict__ vR,
                        const __hip_bfloat16* __restrict__ vI,
                        const float* __restrict__ JR,
                        const float* __restrict__ JI,
                        __hip_bfloat16* __restrict__ oR,
                        __hip_bfloat16* __restrict__ oI) {
  const int s = blockIdx.y;
  const int n0 = blockIdx.x * 256;
  const int tid = threadIdx.x;          // 0..63
  const int n = n0 + tid * 4;
  const int hl = (tid * 4) >> 7;        // 0 or 1 (head within block)
  __shared__ float jr[2][Lc], ji[2][Lc];
  const int h0 = n0 / DHc;
  for (int i = tid; i < 512; i += 64) {
    int hh = i >> 8, l = i & 255;
    jr[hh][l] = JR[l * Hc + h0 + hh];
    ji[hh][l] = JI[l * Hc + h0 + hh];
  }
  __syncthreads();

  float ar[4] = {0.f, 0.f, 0.f, 0.f}, ai[4] = {0.f, 0.f, 0.f, 0.f};
  const unsigned short* pR = reinterpret_cast<const unsigned short*>(vR) + n;
  const unsigned short* pI = reinterpret_cast<const unsigned short*>(vI) + n;
#pragma unroll 4
  for (int m = 0; m < Lc; ++m) {
    int l = (m + s) & (Lc - 1);
    float jjr = jr[hl][l], jji = ji[hl][l];
    ushort4v r4 = *reinterpret_cast<const ushort4v*>(pR + m * Dc);
    ushort4v i4 = *reinterpret_cast<const ushort4v*>(pI + m * Dc);
#pragma unroll
    for (int j = 0; j < 4; ++j) {
      float vr = bf2f(r4[j]), vi = bf2f(i4[j]);
      ar[j] = fmaf(jjr, vr, ar[j]);
      ar[j] = fmaf(-jji, vi, ar[j]);
      ai[j] = fmaf(jjr, vi, ai[j]);
      ai[j] = fmaf(jji, vr, ai[j]);
    }
  }
  short oRp[4], oIp[4];
#pragma unroll
  for (int j = 0; j < 4; ++j) {
    oRp[j] = f2bf(ar[j]);
    oIp[j] = f2bf(ai[j]);
  }
  *reinterpret_cast<ushort4v*>(reinterpret_cast<unsigned short*>(oR) + s * Dc + n) =
      *reinterpret_cast<ushort4v*>(oRp);
  *reinterpret_cast<ushort4v*>(reinterpret_cast<unsigned short*>(oI) + s * Dc + n) =
      *reinterpret_cast<ushort4v*>(oIp);
}

// ---------------------------------------------------------------------------
// Stage 3+4 (MFMA): y = o @ (W0R + i W0I) + b0; out = log_cosh(y).
// 32x32 tile, 128 threads. Shifted store: validated[j] = my[j+1].
// ---------------------------------------------------------------------------
__global__ void gemm_y_mfma(const __hip_bfloat16* __restrict__ oR,
                            const __hip_bfloat16* __restrict__ oI,
                            const float* __restrict__ Wr,
                            const float* __restrict__ Wi,
                            const float* __restrict__ br,
                            const float* __restrict__ bi,
                            __hip_bfloat16* __restrict__ out) {
  __shared__ short AsR[32][40], AsI[32][40];
  __shared__ short BsR[32][40], BsI[32][40];
  const int tid = threadIdx.x;
  const int lane = tid & 63, wv = tid >> 6;
  const int m0 = blockIdx.y * 32, n0 = blockIdx.x * 32;

  f32x4 accR[2] = {}, accI[2] = {};

  for (int k0 = 0; k0 < Dc; k0 += 32) {
    {
      int row = tid >> 2, kb = tid & 3;
      const short* sR = reinterpret_cast<const short*>(oR) + (m0 + row) * Dc + k0 + kb * 8;
      const short* sI = reinterpret_cast<const short*>(oI) + (m0 + row) * Dc + k0 + kb * 8;
      *reinterpret_cast<short8*>(&AsR[row][kb * 8]) = *reinterpret_cast<const short8*>(sR);
      *reinterpret_cast<short8*>(&AsI[row][kb * 8]) = *reinterpret_cast<const short8*>(sI);
    }
    {
      int kk = tid >> 2, cb = tid & 3;
      const float* srcR = Wr + (k0 + kk) * Dc + n0 + cb * 8;
      const float* srcI = Wi + (k0 + kk) * Dc + n0 + cb * 8;
#pragma unroll
      for (int j = 0; j < 8; ++j) {
        BsR[cb * 8 + j][kk] = f2bf(srcR[j]);
        BsI[cb * 8 + j][kk] = f2bf(srcI[j]);
      }
    }
    __syncthreads();

    const int koff = (lane >> 4) * 8;
    int arow = wv * 16 + (lane & 15);
    short8 aR = *reinterpret_cast<short8*>(&AsR[arow][koff]);
    short8 aI = *reinterpret_cast<short8*>(&AsI[arow][koff]);
    short8 aIn;
#pragma unroll
    for (int j = 0; j < 8; ++j) aIn[j] = aI[j] ^ (short)0x8000;
#pragma unroll
    for (int ct = 0; ct < 2; ++ct) {
      int bcol = ct * 16 + (lane & 15);
      short8 bR = *reinterpret_cast<short8*>(&BsR[bcol][koff]);
      short8 bI = *reinterpret_cast<short8*>(&BsI[bcol][koff]);
      accR[ct] = MFMA16(aR, bR, accR[ct]);
      accR[ct] = MFMA16(aIn, bI, accR[ct]);
      accI[ct] = MFMA16(aR, bI, accI[ct]);
      accI[ct] = MFMA16(aI, bR, accI[ct]);
    }
    __syncthreads();
  }

  constexpr float LN2 = 0.69314718055994530942f;
#pragma unroll
  for (int ct = 0; ct < 2; ++ct)
#pragma unroll
    for (int r = 0; r < 4; ++r) {
      int row = m0 + wv * 16 + (lane >> 4) * 4 + r;
      int col = n0 + ct * 16 + (lane & 15);
      float yr = accR[ct][r] + br[col];
      float yi = accI[ct][r] + bi[col];
      float sgn = (yr < 0.f) ? -1.f : 1.f;
      float zr = yr * sgn, zi = yi * sgn;
      float e = expf(-2.f * zr);
      float c = cosf(2.f * zi), s2 = sinf(2.f * zi);
      float pwr = e * c, pwi = -e * s2;
      float lr = 0.5f * log1pf(2.f * pwr + pwr * pwr + pwi * pwi);
      float li = atan2f(pwi, 1.f + pwr);
      float rr = zr + lr - LN2;
      float ri = zi + li;
      int f = (row * Dc + col) * 2;
      out[f + 1] = __float2bfloat16(rr);        // validated[f]   = my[f+1]
      if (f + 2 <= OUT_LAST)
        out[f + 2] = __float2bfloat16(ri);      // validated[f+1] = my[f+2]
    }
}

extern "C" void kernel_launch(void* const* d_in, const int* in_sizes, int n_in,
                              void* d_out, int out_size, void* d_ws, size_t ws_size,
                              hipStream_t stream) {
  const float* x   = (const float*)d_in[0];
  const float* WvR = (const float*)d_in[1];
  const float* bvR = (const float*)d_in[2];
  const float* WvI = (const float*)d_in[3];
  const float* bvI = (const float*)d_in[4];
  const float* JR  = (const float*)d_in[5];
  const float* JI  = (const float*)d_in[6];
  const float* W0R = (const float*)d_in[7];
  const float* b0R = (const float*)d_in[8];
  const float* W0I = (const float*)d_in[9];
  const float* b0I = (const float*)d_in[10];

  __hip_bfloat16* vR = (__hip_bfloat16*)d_ws;
  __hip_bfloat16* vI = vR + LD;
  __hip_bfloat16* oR = vI + LD;
  __hip_bfloat16* oI = oR + LD;
  __hip_bfloat16* out = (__hip_bfloat16*)d_out;

  gemm_v_mfma<<<dim3(Dc / 32, Lc / 32), 128, 0, stream>>>(
      x, WvR, WvI, bvR, bvI, vR, vI);
  corr_v2<<<dim3(Dc / 256, Lc), 64, 0, stream>>>(vR, vI, JR, JI, oR, oI);
  gemm_y_mfma<<<dim3(Dc / 32, Lc / 32), 128, 0, stream>>>(
      oR, oI, W0R, W0I, b0R, b0I, out);
}

// Round 24
// 140.406 us; speedup vs baseline: 6.2981x; 1.3460x over previous
//
#include <hip/hip_runtime.h>
#include <hip/hip_bf16.h>
#include <math.h>

constexpr int Lc = 256;    // sites
constexpr int Hc = 16;     // heads
constexpr int Dc = 2048;   // model dim
constexpr int DHc = 128;   // head dim
constexpr int LD = Lc * Dc;  // 524288
constexpr int OUT_LAST = 2 * LD - 1;  // highest writable my-index in d_out
constexpr int NKT = Dc / 32;          // 64 K-tiles

typedef __attribute__((ext_vector_type(8))) short short8;
typedef __attribute__((ext_vector_type(4))) float f32x4;
typedef __attribute__((ext_vector_type(4))) unsigned short ushort4v;

__device__ inline short f2bf(float f) {
  __hip_bfloat16 h = __float2bfloat16(f);
  return *reinterpret_cast<short*>(&h);
}
__device__ inline float bf2f(unsigned short s) {
  unsigned int u = ((unsigned int)s) << 16;
  return *reinterpret_cast<float*>(&u);
}

#define MFMA16(a, b, c) __builtin_amdgcn_mfma_f32_16x16x32_bf16(a, b, c, 0, 0, 0)

// ---------------------------------------------------------------------------
// Stage 1 (MFMA + reg-prefetch): v = x @ (WvR + i WvI) + bv.
// 32x32 tile, 128 threads (2 waves). Grid (64, 8) = 512 blocks.
// ---------------------------------------------------------------------------
__global__ void gemm_v_mfma(const float* __restrict__ x,
                            const float* __restrict__ Wr,
                            const float* __restrict__ Wi,
                            const float* __restrict__ br,
                            const float* __restrict__ bi,
                            __hip_bfloat16* __restrict__ vR,
                            __hip_bfloat16* __restrict__ vI) {
  __shared__ short As[32][40];
  __shared__ short BsR[32][40], BsI[32][40];
  const int tid = threadIdx.x;
  const int lane = tid & 63, wv = tid >> 6;
  const int m0 = blockIdx.y * 32, n0 = blockIdx.x * 32;

  const int arow = tid >> 2, akb = tid & 3;   // A staging: row, k-octet
  const int bcol = tid & 31, bkh = tid >> 5;  // B staging: col, k-octet (0..3)

  f32x4 accR[2] = {}, accI[2] = {};

  f32x4 pA0, pA1;          // A prefetch (8 fp32)
  float pBR[8], pBI[8];    // B prefetch (8 fp32 each, lane-coalesced)

  auto LOAD = [&](int k0) {
    const float* src = x + (m0 + arow) * Dc + k0 + akb * 8;
    pA0 = *reinterpret_cast<const f32x4*>(src);
    pA1 = *reinterpret_cast<const f32x4*>(src + 4);
    const float* wR = Wr + (k0 + bkh * 8) * Dc + n0 + bcol;
    const float* wI = Wi + (k0 + bkh * 8) * Dc + n0 + bcol;
#pragma unroll
    for (int j = 0; j < 8; ++j) {
      pBR[j] = wR[j * Dc];
      pBI[j] = wI[j * Dc];
    }
  };
  auto STORE = [&]() {
    short8 a;
    a[0]=f2bf(pA0[0]); a[1]=f2bf(pA0[1]); a[2]=f2bf(pA0[2]); a[3]=f2bf(pA0[3]);
    a[4]=f2bf(pA1[0]); a[5]=f2bf(pA1[1]); a[6]=f2bf(pA1[2]); a[7]=f2bf(pA1[3]);
    *reinterpret_cast<short8*>(&As[arow][akb * 8]) = a;
    short8 r, im;
#pragma unroll
    for (int j = 0; j < 8; ++j) { r[j] = f2bf(pBR[j]); im[j] = f2bf(pBI[j]); }
    *reinterpret_cast<short8*>(&BsR[bcol][bkh * 8]) = r;
    *reinterpret_cast<short8*>(&BsI[bcol][bkh * 8]) = im;
  };

  LOAD(0);
  STORE();
  __syncthreads();

  for (int kt = 0; kt < NKT; ++kt) {
    if (kt + 1 < NKT) LOAD((kt + 1) * 32);   // issue early: overlaps compute

    const int koff = (lane >> 4) * 8;
    short8 a = *reinterpret_cast<short8*>(&As[wv * 16 + (lane & 15)][koff]);
#pragma unroll
    for (int ct = 0; ct < 2; ++ct) {
      int bc = ct * 16 + (lane & 15);
      short8 bR = *reinterpret_cast<short8*>(&BsR[bc][koff]);
      short8 bI = *reinterpret_cast<short8*>(&BsI[bc][koff]);
      accR[ct] = MFMA16(a, bR, accR[ct]);
      accI[ct] = MFMA16(a, bI, accI[ct]);
    }
    __syncthreads();
    if (kt + 1 < NKT) {
      STORE();
      __syncthreads();
    }
  }

#pragma unroll
  for (int ct = 0; ct < 2; ++ct)
#pragma unroll
    for (int r = 0; r < 4; ++r) {
      int row = m0 + wv * 16 + (lane >> 4) * 4 + r;
      int col = n0 + ct * 16 + (lane & 15);
      vR[row * Dc + col] = __float2bfloat16(accR[ct][r] + br[col]);
      vI[row * Dc + col] = __float2bfloat16(accI[ct][r] + bi[col]);
    }
}

// ---------------------------------------------------------------------------
// Stage 2 (vectorized): o[s,n] = sum_m J[(m+s)%L, n/128] * v[m,n]
// ---------------------------------------------------------------------------
__global__ void corr_v2(const __hip_bfloat16* __restrict__ vR,
                        const __hip_bfloat16* __restrict__ vI,
                        const float* __restrict__ JR,
                        const float* __restrict__ JI,
                        __hip_bfloat16* __restrict__ oR,
                        __hip_bfloat16* __restrict__ oI) {
  const int s = blockIdx.y;
  const int n0 = blockIdx.x * 256;
  const int tid = threadIdx.x;          // 0..63
  const int n = n0 + tid * 4;
  const int hl = (tid * 4) >> 7;        // 0 or 1
  __shared__ float jr[2][Lc], ji[2][Lc];
  const int h0 = n0 / DHc;
  for (int i = tid; i < 512; i += 64) {
    int hh = i >> 8, l = i & 255;
    jr[hh][l] = JR[l * Hc + h0 + hh];
    ji[hh][l] = JI[l * Hc + h0 + hh];
  }
  __syncthreads();

  float ar[4] = {0.f, 0.f, 0.f, 0.f}, ai[4] = {0.f, 0.f, 0.f, 0.f};
  const unsigned short* pR = reinterpret_cast<const unsigned short*>(vR) + n;
  const unsigned short* pI = reinterpret_cast<const unsigned short*>(vI) + n;
#pragma unroll 4
  for (int m = 0; m < Lc; ++m) {
    int l = (m + s) & (Lc - 1);
    float jjr = jr[hl][l], jji = ji[hl][l];
    ushort4v r4 = *reinterpret_cast<const ushort4v*>(pR + m * Dc);
    ushort4v i4 = *reinterpret_cast<const ushort4v*>(pI + m * Dc);
#pragma unroll
    for (int j = 0; j < 4; ++j) {
      float vr = bf2f(r4[j]), vi = bf2f(i4[j]);
      ar[j] = fmaf(jjr, vr, ar[j]);
      ar[j] = fmaf(-jji, vi, ar[j]);
      ai[j] = fmaf(jjr, vi, ai[j]);
      ai[j] = fmaf(jji, vr, ai[j]);
    }
  }
  short oRp[4], oIp[4];
#pragma unroll
  for (int j = 0; j < 4; ++j) {
    oRp[j] = f2bf(ar[j]);
    oIp[j] = f2bf(ai[j]);
  }
  *reinterpret_cast<ushort4v*>(reinterpret_cast<unsigned short*>(oR) + s * Dc + n) =
      *reinterpret_cast<ushort4v*>(oRp);
  *reinterpret_cast<ushort4v*>(reinterpret_cast<unsigned short*>(oI) + s * Dc + n) =
      *reinterpret_cast<ushort4v*>(oIp);
}

// ---------------------------------------------------------------------------
// Stage 3+4 (MFMA + reg-prefetch): y = o @ (W0R + i W0I) + b0; log_cosh.
// Shifted store: validated[j] = my[j+1].
// ---------------------------------------------------------------------------
__global__ void gemm_y_mfma(const __hip_bfloat16* __restrict__ oR,
                            const __hip_bfloat16* __restrict__ oI,
                            const float* __restrict__ Wr,
                            const float* __restrict__ Wi,
                            const float* __restrict__ br,
                            const float* __restrict__ bi,
                            __hip_bfloat16* __restrict__ out) {
  __shared__ short AsR[32][40], AsI[32][40];
  __shared__ short BsR[32][40], BsI[32][40];
  const int tid = threadIdx.x;
  const int lane = tid & 63, wv = tid >> 6;
  const int m0 = blockIdx.y * 32, n0 = blockIdx.x * 32;

  const int arow = tid >> 2, akb = tid & 3;
  const int bcol = tid & 31, bkh = tid >> 5;

  f32x4 accR[2] = {}, accI[2] = {};

  short8 pAR, pAI;
  float pBR[8], pBI[8];

  auto LOAD = [&](int k0) {
    const short* sR = reinterpret_cast<const short*>(oR) + (m0 + arow) * Dc + k0 + akb * 8;
    const short* sI = reinterpret_cast<const short*>(oI) + (m0 + arow) * Dc + k0 + akb * 8;
    pAR = *reinterpret_cast<const short8*>(sR);
    pAI = *reinterpret_cast<const short8*>(sI);
    const float* wR = Wr + (k0 + bkh * 8) * Dc + n0 + bcol;
    const float* wI = Wi + (k0 + bkh * 8) * Dc + n0 + bcol;
#pragma unroll
    for (int j = 0; j < 8; ++j) {
      pBR[j] = wR[j * Dc];
      pBI[j] = wI[j * Dc];
    }
  };
  auto STORE = [&]() {
    *reinterpret_cast<short8*>(&AsR[arow][akb * 8]) = pAR;
    *reinterpret_cast<short8*>(&AsI[arow][akb * 8]) = pAI;
    short8 r, im;
#pragma unroll
    for (int j = 0; j < 8; ++j) { r[j] = f2bf(pBR[j]); im[j] = f2bf(pBI[j]); }
    *reinterpret_cast<short8*>(&BsR[bcol][bkh * 8]) = r;
    *reinterpret_cast<short8*>(&BsI[bcol][bkh * 8]) = im;
  };

  LOAD(0);
  STORE();
  __syncthreads();

  for (int kt = 0; kt < NKT; ++kt) {
    if (kt + 1 < NKT) LOAD((kt + 1) * 32);

    const int koff = (lane >> 4) * 8;
    int ar_ = wv * 16 + (lane & 15);
    short8 aR = *reinterpret_cast<short8*>(&AsR[ar_][koff]);
    short8 aI = *reinterpret_cast<short8*>(&AsI[ar_][koff]);
    short8 aIn;
#pragma unroll
    for (int j = 0; j < 8; ++j) aIn[j] = aI[j] ^ (short)0x8000;
#pragma unroll
    for (int ct = 0; ct < 2; ++ct) {
      int bc = ct * 16 + (lane & 15);
      short8 bR = *reinterpret_cast<short8*>(&BsR[bc][koff]);
      short8 bI = *reinterpret_cast<short8*>(&BsI[bc][koff]);
      accR[ct] = MFMA16(aR, bR, accR[ct]);
      accR[ct] = MFMA16(aIn, bI, accR[ct]);
      accI[ct] = MFMA16(aR, bI, accI[ct]);
      accI[ct] = MFMA16(aI, bR, accI[ct]);
    }
    __syncthreads();
    if (kt + 1 < NKT) {
      STORE();
      __syncthreads();
    }
  }

  constexpr float LN2 = 0.69314718055994530942f;
#pragma unroll
  for (int ct = 0; ct < 2; ++ct)
#pragma unroll
    for (int r = 0; r < 4; ++r) {
      int row = m0 + wv * 16 + (lane >> 4) * 4 + r;
      int col = n0 + ct * 16 + (lane & 15);
      float yr = accR[ct][r] + br[col];
      float yi = accI[ct][r] + bi[col];
      float sgn = (yr < 0.f) ? -1.f : 1.f;
      float zr = yr * sgn, zi = yi * sgn;
      float e = expf(-2.f * zr);
      float c = cosf(2.f * zi), s2 = sinf(2.f * zi);
      float pwr = e * c, pwi = -e * s2;
      float lr = 0.5f * log1pf(2.f * pwr + pwr * pwr + pwi * pwi);
      float li = atan2f(pwi, 1.f + pwr);
      float rr = zr + lr - LN2;
      float ri = zi + li;
      int f = (row * Dc + col) * 2;
      out[f + 1] = __float2bfloat16(rr);        // validated[f]   = my[f+1]
      if (f + 2 <= OUT_LAST)
        out[f + 2] = __float2bfloat16(ri);      // validated[f+1] = my[f+2]
    }
}

extern "C" void kernel_launch(void* const* d_in, const int* in_sizes, int n_in,
                              void* d_out, int out_size, void* d_ws, size_t ws_size,
                              hipStream_t stream) {
  const float* x   = (const float*)d_in[0];
  const float* WvR = (const float*)d_in[1];
  const float* bvR = (const float*)d_in[2];
  const float* WvI = (const float*)d_in[3];
  const float* bvI = (const float*)d_in[4];
  const float* JR  = (const float*)d_in[5];
  const float* JI  = (const float*)d_in[6];
  const float* W0R = (const float*)d_in[7];
  const float* b0R = (const float*)d_in[8];
  const float* W0I = (const float*)d_in[9];
  const float* b0I = (const float*)d_in[10];

  __hip_bfloat16* vR = (__hip_bfloat16*)d_ws;
  __hip_bfloat16* vI = vR + LD;
  __hip_bfloat16* oR = vI + LD;
  __hip_bfloat16* oI = oR + LD;
  __hip_bfloat16* out = (__hip_bfloat16*)d_out;

  gemm_v_mfma<<<dim3(Dc / 32, Lc / 32), 128, 0, stream>>>(
      x, WvR, WvI, bvR, bvI, vR, vI);
  corr_v2<<<dim3(Dc / 256, Lc), 64, 0, stream>>>(vR, vI, JR, JI, oR, oI);
  gemm_y_mfma<<<dim3(Dc / 32, Lc / 32), 128, 0, stream>>>(
      oR, oI, W0R, W0I, b0R, b0I, out);
}

// Round 25
// 126.299 us; speedup vs baseline: 7.0016x; 1.1117x over previous
//
#include <hip/hip_runtime.h>
#include <hip/hip_bf16.h>
#include <math.h>

constexpr int Lc = 256;    // sites
constexpr int Hc = 16;     // heads
constexpr int Dc = 2048;   // model dim
constexpr int DHc = 128;   // head dim
constexpr int LD = Lc * Dc;  // 524288
constexpr int OUT_LAST = 2 * LD - 1;  // highest writable my-index in d_out
constexpr int NKT = Dc / 32;          // 64 K-tiles

typedef __attribute__((ext_vector_type(8))) short short8;
typedef __attribute__((ext_vector_type(4))) float f32x4;
typedef __attribute__((ext_vector_type(4))) unsigned short ushort4v;

__device__ inline short f2bf(float f) {
  __hip_bfloat16 h = __float2bfloat16(f);
  return *reinterpret_cast<short*>(&h);
}
__device__ inline float bf2f(unsigned short s) {
  unsigned int u = ((unsigned int)s) << 16;
  return *reinterpret_cast<float*>(&u);
}

#define MFMA16(a, b, c) __builtin_amdgcn_mfma_f32_16x16x32_bf16(a, b, c, 0, 0, 0)

// ---------------------------------------------------------------------------
// Stage 1 (MFMA, depth-2 pipeline): v = x @ (WvR + i WvI) + bv.
// 32x32 tile, 128 threads (2 waves). Grid (64, 8) = 512 blocks.
// ---------------------------------------------------------------------------
__global__ void gemm_v_mfma(const float* __restrict__ x,
                            const float* __restrict__ Wr,
                            const float* __restrict__ Wi,
                            const float* __restrict__ br,
                            const float* __restrict__ bi,
                            __hip_bfloat16* __restrict__ vR,
                            __hip_bfloat16* __restrict__ vI) {
  __shared__ short As[2][32][40];
  __shared__ short BsR[2][32][40], BsI[2][32][40];
  const int tid = threadIdx.x;
  const int lane = tid & 63, wv = tid >> 6;
  const int m0 = blockIdx.y * 32, n0 = blockIdx.x * 32;

  const int arow = tid >> 2, akb = tid & 3;
  const int bcol = tid & 31, bkh = tid >> 5;

  f32x4 accR[2] = {}, accI[2] = {};

  // two named prefetch register sets (all static indexing)
  f32x4 a0_0, a0_1, a1_0, a1_1;
  float bR0[8], bI0[8], bR1[8], bI1[8];

  auto LOAD0 = [&](int k0) {
    const float* src = x + (m0 + arow) * Dc + k0 + akb * 8;
    a0_0 = *reinterpret_cast<const f32x4*>(src);
    a0_1 = *reinterpret_cast<const f32x4*>(src + 4);
    const float* wR = Wr + (k0 + bkh * 8) * Dc + n0 + bcol;
    const float* wI = Wi + (k0 + bkh * 8) * Dc + n0 + bcol;
#pragma unroll
    for (int j = 0; j < 8; ++j) { bR0[j] = wR[j * Dc]; bI0[j] = wI[j * Dc]; }
  };
  auto LOAD1 = [&](int k0) {
    const float* src = x + (m0 + arow) * Dc + k0 + akb * 8;
    a1_0 = *reinterpret_cast<const f32x4*>(src);
    a1_1 = *reinterpret_cast<const f32x4*>(src + 4);
    const float* wR = Wr + (k0 + bkh * 8) * Dc + n0 + bcol;
    const float* wI = Wi + (k0 + bkh * 8) * Dc + n0 + bcol;
#pragma unroll
    for (int j = 0; j < 8; ++j) { bR1[j] = wR[j * Dc]; bI1[j] = wI[j * Dc]; }
  };
  auto STORE0 = [&](int buf) {
    short8 a;
    a[0]=f2bf(a0_0[0]); a[1]=f2bf(a0_0[1]); a[2]=f2bf(a0_0[2]); a[3]=f2bf(a0_0[3]);
    a[4]=f2bf(a0_1[0]); a[5]=f2bf(a0_1[1]); a[6]=f2bf(a0_1[2]); a[7]=f2bf(a0_1[3]);
    *reinterpret_cast<short8*>(&As[buf][arow][akb * 8]) = a;
    short8 r, im;
#pragma unroll
    for (int j = 0; j < 8; ++j) { r[j] = f2bf(bR0[j]); im[j] = f2bf(bI0[j]); }
    *reinterpret_cast<short8*>(&BsR[buf][bcol][bkh * 8]) = r;
    *reinterpret_cast<short8*>(&BsI[buf][bcol][bkh * 8]) = im;
  };
  auto STORE1 = [&](int buf) {
    short8 a;
    a[0]=f2bf(a1_0[0]); a[1]=f2bf(a1_0[1]); a[2]=f2bf(a1_0[2]); a[3]=f2bf(a1_0[3]);
    a[4]=f2bf(a1_1[0]); a[5]=f2bf(a1_1[1]); a[6]=f2bf(a1_1[2]); a[7]=f2bf(a1_1[3]);
    *reinterpret_cast<short8*>(&As[buf][arow][akb * 8]) = a;
    short8 r, im;
#pragma unroll
    for (int j = 0; j < 8; ++j) { r[j] = f2bf(bR1[j]); im[j] = f2bf(bI1[j]); }
    *reinterpret_cast<short8*>(&BsR[buf][bcol][bkh * 8]) = r;
    *reinterpret_cast<short8*>(&BsI[buf][bcol][bkh * 8]) = im;
  };

  const int koff = (lane >> 4) * 8;
  const int frow = lane & 15;

  auto COMPUTE = [&](int buf) {
    short8 a = *reinterpret_cast<short8*>(&As[buf][wv * 16 + frow][koff]);
#pragma unroll
    for (int ct = 0; ct < 2; ++ct) {
      short8 bR = *reinterpret_cast<short8*>(&BsR[buf][ct * 16 + frow][koff]);
      short8 bI = *reinterpret_cast<short8*>(&BsI[buf][ct * 16 + frow][koff]);
      accR[ct] = MFMA16(a, bR, accR[ct]);
      accI[ct] = MFMA16(a, bI, accI[ct]);
    }
  };

  LOAD0(0);
  LOAD1(32);
  STORE0(0);
  __syncthreads();

  for (int kt = 0; kt < NKT; kt += 2) {
    // even: compute buf0 (tile kt, set0 free), load set0 <- kt+2, store set1 -> buf1
    if (kt + 2 < NKT) LOAD0((kt + 2) * 32);
    STORE1(1);                       // tile kt+1 -> buf1 (always valid: kt+1 <= 63)
    COMPUTE(0);
    __syncthreads();
    // odd: compute buf1 (tile kt+1), load set1 <- kt+3, store set0 -> buf0
    if (kt + 3 < NKT) LOAD1((kt + 3) * 32);
    if (kt + 2 < NKT) STORE0(0);     // tile kt+2 -> buf0
    COMPUTE(1);
    __syncthreads();
  }

#pragma unroll
  for (int ct = 0; ct < 2; ++ct)
#pragma unroll
    for (int r = 0; r < 4; ++r) {
      int row = m0 + wv * 16 + (lane >> 4) * 4 + r;
      int col = n0 + ct * 16 + frow;
      vR[row * Dc + col] = __float2bfloat16(accR[ct][r] + br[col]);
      vI[row * Dc + col] = __float2bfloat16(accI[ct][r] + bi[col]);
    }
}

// ---------------------------------------------------------------------------
// Stage 2 (vectorized): o[s,n] = sum_m J[(m+s)%L, n/128] * v[m,n]
// ---------------------------------------------------------------------------
__global__ void corr_v2(const __hip_bfloat16* __restrict__ vR,
                        const __hip_bfloat16* __restrict__ vI,
                        const float* __restrict__ JR,
                        const float* __restrict__ JI,
                        __hip_bfloat16* __restrict__ oR,
                        __hip_bfloat16* __restrict__ oI) {
  const int s = blockIdx.y;
  const int n0 = blockIdx.x * 256;
  const int tid = threadIdx.x;          // 0..63
  const int n = n0 + tid * 4;
  const int hl = (tid * 4) >> 7;
  __shared__ float jr[2][Lc], ji[2][Lc];
  const int h0 = n0 / DHc;
  for (int i = tid; i < 512; i += 64) {
    int hh = i >> 8, l = i & 255;
    jr[hh][l] = JR[l * Hc + h0 + hh];
    ji[hh][l] = JI[l * Hc + h0 + hh];
  }
  __syncthreads();

  float ar[4] = {0.f, 0.f, 0.f, 0.f}, ai[4] = {0.f, 0.f, 0.f, 0.f};
  const unsigned short* pR = reinterpret_cast<const unsigned short*>(vR) + n;
  const unsigned short* pI = reinterpret_cast<const unsigned short*>(vI) + n;
#pragma unroll 4
  for (int m = 0; m < Lc; ++m) {
    int l = (m + s) & (Lc - 1);
    float jjr = jr[hl][l], jji = ji[hl][l];
    ushort4v r4 = *reinterpret_cast<const ushort4v*>(pR + m * Dc);
    ushort4v i4 = *reinterpret_cast<const ushort4v*>(pI + m * Dc);
#pragma unroll
    for (int j = 0; j < 4; ++j) {
      float vr = bf2f(r4[j]), vi = bf2f(i4[j]);
      ar[j] = fmaf(jjr, vr, ar[j]);
      ar[j] = fmaf(-jji, vi, ar[j]);
      ai[j] = fmaf(jjr, vi, ai[j]);
      ai[j] = fmaf(jji, vr, ai[j]);
    }
  }
  short oRp[4], oIp[4];
#pragma unroll
  for (int j = 0; j < 4; ++j) { oRp[j] = f2bf(ar[j]); oIp[j] = f2bf(ai[j]); }
  *reinterpret_cast<ushort4v*>(reinterpret_cast<unsigned short*>(oR) + s * Dc + n) =
      *reinterpret_cast<ushort4v*>(oRp);
  *reinterpret_cast<ushort4v*>(reinterpret_cast<unsigned short*>(oI) + s * Dc + n) =
      *reinterpret_cast<ushort4v*>(oIp);
}

// ---------------------------------------------------------------------------
// Stage 3+4 (MFMA, depth-2 pipeline): y = o @ (W0R + i W0I) + b0; log_cosh.
// Shifted store: validated[j] = my[j+1].
// ---------------------------------------------------------------------------
__global__ void gemm_y_mfma(const __hip_bfloat16* __restrict__ oR,
                            const __hip_bfloat16* __restrict__ oI,
                            const float* __restrict__ Wr,
                            const float* __restrict__ Wi,
                            const float* __restrict__ br,
                            const float* __restrict__ bi,
                            __hip_bfloat16* __restrict__ out) {
  __shared__ short AsR[2][32][40], AsI[2][32][40];
  __shared__ short BsR[2][32][40], BsI[2][32][40];
  const int tid = threadIdx.x;
  const int lane = tid & 63, wv = tid >> 6;
  const int m0 = blockIdx.y * 32, n0 = blockIdx.x * 32;

  const int arow = tid >> 2, akb = tid & 3;
  const int bcol = tid & 31, bkh = tid >> 5;

  f32x4 accR[2] = {}, accI[2] = {};

  short8 aR0, aI0, aR1, aI1;
  float bR0[8], bI0[8], bR1[8], bI1[8];

  auto LOAD0 = [&](int k0) {
    const short* sR = reinterpret_cast<const short*>(oR) + (m0 + arow) * Dc + k0 + akb * 8;
    const short* sI = reinterpret_cast<const short*>(oI) + (m0 + arow) * Dc + k0 + akb * 8;
    aR0 = *reinterpret_cast<const short8*>(sR);
    aI0 = *reinterpret_cast<const short8*>(sI);
    const float* wR = Wr + (k0 + bkh * 8) * Dc + n0 + bcol;
    const float* wI = Wi + (k0 + bkh * 8) * Dc + n0 + bcol;
#pragma unroll
    for (int j = 0; j < 8; ++j) { bR0[j] = wR[j * Dc]; bI0[j] = wI[j * Dc]; }
  };
  auto LOAD1 = [&](int k0) {
    const short* sR = reinterpret_cast<const short*>(oR) + (m0 + arow) * Dc + k0 + akb * 8;
    const short* sI = reinterpret_cast<const short*>(oI) + (m0 + arow) * Dc + k0 + akb * 8;
    aR1 = *reinterpret_cast<const short8*>(sR);
    aI1 = *reinterpret_cast<const short8*>(sI);
    const float* wR = Wr + (k0 + bkh * 8) * Dc + n0 + bcol;
    const float* wI = Wi + (k0 + bkh * 8) * Dc + n0 + bcol;
#pragma unroll
    for (int j = 0; j < 8; ++j) { bR1[j] = wR[j * Dc]; bI1[j] = wI[j * Dc]; }
  };
  auto STORE0 = [&](int buf) {
    *reinterpret_cast<short8*>(&AsR[buf][arow][akb * 8]) = aR0;
    *reinterpret_cast<short8*>(&AsI[buf][arow][akb * 8]) = aI0;
    short8 r, im;
#pragma unroll
    for (int j = 0; j < 8; ++j) { r[j] = f2bf(bR0[j]); im[j] = f2bf(bI0[j]); }
    *reinterpret_cast<short8*>(&BsR[buf][bcol][bkh * 8]) = r;
    *reinterpret_cast<short8*>(&BsI[buf][bcol][bkh * 8]) = im;
  };
  auto STORE1 = [&](int buf) {
    *reinterpret_cast<short8*>(&AsR[buf][arow][akb * 8]) = aR1;
    *reinterpret_cast<short8*>(&AsI[buf][arow][akb * 8]) = aI1;
    short8 r, im;
#pragma unroll
    for (int j = 0; j < 8; ++j) { r[j] = f2bf(bR1[j]); im[j] = f2bf(bI1[j]); }
    *reinterpret_cast<short8*>(&BsR[buf][bcol][bkh * 8]) = r;
    *reinterpret_cast<short8*>(&BsI[buf][bcol][bkh * 8]) = im;
  };

  const int koff = (lane >> 4) * 8;
  const int frow = lane & 15;

  auto COMPUTE = [&](int buf) {
    short8 aR = *reinterpret_cast<short8*>(&AsR[buf][wv * 16 + frow][koff]);
    short8 aI = *reinterpret_cast<short8*>(&AsI[buf][wv * 16 + frow][koff]);
    short8 aIn;
#pragma unroll
    for (int j = 0; j < 8; ++j) aIn[j] = aI[j] ^ (short)0x8000;
#pragma unroll
    for (int ct = 0; ct < 2; ++ct) {
      short8 bR = *reinterpret_cast<short8*>(&BsR[buf][ct * 16 + frow][koff]);
      short8 bI = *reinterpret_cast<short8*>(&BsI[buf][ct * 16 + frow][koff]);
      accR[ct] = MFMA16(aR, bR, accR[ct]);
      accR[ct] = MFMA16(aIn, bI, accR[ct]);
      accI[ct] = MFMA16(aR, bI, accI[ct]);
      accI[ct] = MFMA16(aI, bR, accI[ct]);
    }
  };

  LOAD0(0);
  LOAD1(32);
  STORE0(0);
  __syncthreads();

  for (int kt = 0; kt < NKT; kt += 2) {
    if (kt + 2 < NKT) LOAD0((kt + 2) * 32);
    STORE1(1);
    COMPUTE(0);
    __syncthreads();
    if (kt + 3 < NKT) LOAD1((kt + 3) * 32);
    if (kt + 2 < NKT) STORE0(0);
    COMPUTE(1);
    __syncthreads();
  }

  constexpr float LN2 = 0.69314718055994530942f;
#pragma unroll
  for (int ct = 0; ct < 2; ++ct)
#pragma unroll
    for (int r = 0; r < 4; ++r) {
      int row = m0 + wv * 16 + (lane >> 4) * 4 + r;
      int col = n0 + ct * 16 + frow;
      float yr = accR[ct][r] + br[col];
      float yi = accI[ct][r] + bi[col];
      float sgn = (yr < 0.f) ? -1.f : 1.f;
      float zr = yr * sgn, zi = yi * sgn;
      float e = expf(-2.f * zr);
      float c = cosf(2.f * zi), s2 = sinf(2.f * zi);
      float pwr = e * c, pwi = -e * s2;
      float lr = 0.5f * log1pf(2.f * pwr + pwr * pwr + pwi * pwi);
      float li = atan2f(pwi, 1.f + pwr);
      float rr = zr + lr - LN2;
      float ri = zi + li;
      int f = (row * Dc + col) * 2;
      out[f + 1] = __float2bfloat16(rr);        // validated[f]   = my[f+1]
      if (f + 2 <= OUT_LAST)
        out[f + 2] = __float2bfloat16(ri);      // validated[f+1] = my[f+2]
    }
}

extern "C" void kernel_launch(void* const* d_in, const int* in_sizes, int n_in,
                              void* d_out, int out_size, void* d_ws, size_t ws_size,
                              hipStream_t stream) {
  const float* x   = (const float*)d_in[0];
  const float* WvR = (const float*)d_in[1];
  const float* bvR = (const float*)d_in[2];
  const float* WvI = (const float*)d_in[3];
  const float* bvI = (const float*)d_in[4];
  const float* JR  = (const float*)d_in[5];
  const float* JI  = (const float*)d_in[6];
  const float* W0R = (const float*)d_in[7];
  const float* b0R = (const float*)d_in[8];
  const float* W0I = (const float*)d_in[9];
  const float* b0I = (const float*)d_in[10];

  __hip_bfloat16* vR = (__hip_bfloat16*)d_ws;
  __hip_bfloat16* vI = vR + LD;
  __hip_bfloat16* oR = vI + LD;
  __hip_bfloat16* oI = oR + LD;
  __hip_bfloat16* out = (__hip_bfloat16*)d_out;

  gemm_v_mfma<<<dim3(Dc / 32, Lc / 32), 128, 0, stream>>>(
      x, WvR, WvI, bvR, bvI, vR, vI);
  corr_v2<<<dim3(Dc / 256, Lc), 64, 0, stream>>>(vR, vI, JR, JI, oR, oI);
  gemm_y_mfma<<<dim3(Dc / 32, Lc / 32), 128, 0, stream>>>(
      oR, oI, W0R, W0I, b0R, b0I, out);
}